// Round 1
// baseline (399.018 us; speedup 1.0000x reference)
//
#include <hip/hip_runtime.h>
#include <math.h>

// KPConv fused kernel for MI355X (gfx950).
// Shapes (from setup_inputs): N=50000, M=50000, H=40, K=15, CIN=64, COUT=128.
constexpr int H    = 40;
constexpr int KKP  = 15;
constexpr int CIN  = 64;
constexpr int COUT = 128;
constexpr int QB   = 8;      // queries per block
constexpr float KP_EXT = 1.2f;

// ---------------- kernel 1: per-support-row feature sums (validity) -------------
__global__ __launch_bounds__(256) void rowsum_kernel(const float* __restrict__ x,
                                                     float* __restrict__ rowsum, int M) {
    int row  = blockIdx.x * 4 + (threadIdx.x >> 6);
    int lane = threadIdx.x & 63;
    if (row >= M) return;
    float v = x[row * CIN + lane];   // CIN == 64 == wave width
    #pragma unroll
    for (int off = 32; off > 0; off >>= 1) v += __shfl_down(v, off, 64);
    if (lane == 0) rowsum[row] = v;
}

// ---------------- kernel 2: fused KPConv ---------------------------------------
// LDS carve (floats):
//   WF_T   [960][8]    : 7680      (offset 0)
//   inds_s [QB*H] ints : 320       (offset 7680)
//   w_s    [QB*H][16]  : 5120      (offset 8000)
//   cnt    [QB] ints   : 8         (offset 13120)
//   scratch[8][128][9] : 9216      (offset 0, overlaps WF_T/inds/w after barrier)
__global__ __launch_bounds__(256) void kpconv_main(
    const float* __restrict__ q_pts, const float* __restrict__ s_pts,
    const int*   __restrict__ nbinds, const float* __restrict__ x,
    const float* __restrict__ kp,     const float* __restrict__ wmat,
    const float* __restrict__ rowsum, float* __restrict__ out,
    int N, int M)
{
    __shared__ float smem[13128];
    float* WF_T    = smem;                    // [960][8]
    int*   inds_s  = (int*)(smem + 7680);     // [QB][H]
    float* w_s     = smem + 8000;             // [QB][H][16]
    int*   cnt     = (int*)(smem + 13120);    // [QB]
    float* scratch = smem;                    // [8][128][9] (after WF_T is dead)

    const int tid = threadIdx.x;
    const int q0  = blockIdx.x * QB;

    if (tid < QB) cnt[tid] = 0;
    __syncthreads();

    // ---------------- Phase A: per-(q,h) kernel-point weights + validity -------
    for (int p = tid; p < QB * H; p += 256) {
        int q  = p / H;
        int h  = p - q * H;
        int gq = q0 + q;
        int ind = (gq < N) ? nbinds[gq * H + h] : M;   // out-of-range -> shadow
        inds_s[p] = ind;
        float nx = 0.f, ny = 0.f, nz = 0.f;
        bool shadow = (ind >= M);
        if (!shadow) {
            float qx = q_pts[gq * 3 + 0], qy = q_pts[gq * 3 + 1], qz = q_pts[gq * 3 + 2];
            nx = s_pts[ind * 3 + 0] - qx;
            ny = s_pts[ind * 3 + 1] - qy;
            nz = s_pts[ind * 3 + 2] - qz;
            if (rowsum[ind] > 0.0f) atomicAdd(&cnt[q], 1);
        }
        float n2 = nx * nx + ny * ny + nz * nz;
        #pragma unroll
        for (int k = 0; k < 16; ++k) {
            float wv = 0.f;
            if (k < KKP && !shadow) {
                float kx = kp[k * 3 + 0], ky = kp[k * 3 + 1], kz = kp[k * 3 + 2];
                float k2 = kx * kx + ky * ky + kz * kz;
                float cross = nx * kx + ny * ky + nz * kz;
                float sq = fmaxf(n2 + k2 - 2.0f * cross, 0.0f);   // same formula as ref
                wv = fmaxf(1.0f - sqrtf(sq) / KP_EXT, 0.0f);
            }
            w_s[p * 16 + k] = wv;
        }
    }
    __syncthreads();

    // ---------------- Phase B: WF[q][k][c] accumulation ------------------------
    // thread = (wave ql = q-in-group, lane c). Two rounds cover QB=8 queries.
    {
        const int ql = tid >> 6;   // 0..3 (wave id)
        const int c  = tid & 63;
        for (int r = 0; r < 2; ++r) {
            int q = r * 4 + ql;
            float acc[15];
            #pragma unroll
            for (int k = 0; k < 15; ++k) acc[k] = 0.f;
            for (int h = 0; h < H; ++h) {
                int ind = inds_s[q * H + h];
                const float4* w4 = (const float4*)&w_s[(q * H + h) * 16];
                float4 w0 = w4[0], w1 = w4[1], w2 = w4[2], w3 = w4[3];
                // wave-uniform skip of all-zero weight rows (~most rows)
                float m0 = fmaxf(fmaxf(w0.x, w0.y), fmaxf(w0.z, w0.w));
                float m1 = fmaxf(fmaxf(w1.x, w1.y), fmaxf(w1.z, w1.w));
                float m2 = fmaxf(fmaxf(w2.x, w2.y), fmaxf(w2.z, w2.w));
                float m3 = fmaxf(fmaxf(w3.x, w3.y), w3.z);
                float mx = fmaxf(fmaxf(m0, m1), fmaxf(m2, m3));
                if (mx > 0.f && ind < M) {
                    float xv = x[ind * CIN + c];
                    acc[0]  += w0.x * xv; acc[1]  += w0.y * xv;
                    acc[2]  += w0.z * xv; acc[3]  += w0.w * xv;
                    acc[4]  += w1.x * xv; acc[5]  += w1.y * xv;
                    acc[6]  += w1.z * xv; acc[7]  += w1.w * xv;
                    acc[8]  += w2.x * xv; acc[9]  += w2.y * xv;
                    acc[10] += w2.z * xv; acc[11] += w2.w * xv;
                    acc[12] += w3.x * xv; acc[13] += w3.y * xv;
                    acc[14] += w3.z * xv;
                }
            }
            #pragma unroll
            for (int k = 0; k < 15; ++k) WF_T[(k * 64 + c) * 8 + q] = acc[k];
        }
    }
    __syncthreads();

    // ---------------- Phase C: out[q][o] = sum_j WF_T[j][q] * W[j][o] ----------
    // thread = (og = o/4 group of 4 outputs, jc = j-chunk of 120)
    const int og = tid & 31;
    const int jc = tid >> 5;
    float acc2[4][8];
    #pragma unroll
    for (int oi = 0; oi < 4; ++oi)
        #pragma unroll
        for (int qi = 0; qi < 8; ++qi) acc2[oi][qi] = 0.f;

    const float4* wm4 = (const float4*)wmat;   // [960][32] float4 view
    const int jbase = jc * 120;
    for (int jj = 0; jj < 120; ++jj) {
        int j = jbase + jj;
        float4 wv = wm4[j * 32 + og];
        float4 a  = *(const float4*)&WF_T[j * 8 + 0];
        float4 b  = *(const float4*)&WF_T[j * 8 + 4];
        float qv[8] = {a.x, a.y, a.z, a.w, b.x, b.y, b.z, b.w};
        float ov[4] = {wv.x, wv.y, wv.z, wv.w};
        #pragma unroll
        for (int oi = 0; oi < 4; ++oi)
            #pragma unroll
            for (int qi = 0; qi < 8; ++qi)
                acc2[oi][qi] += ov[oi] * qv[qi];
    }
    __syncthreads();   // WF_T dead; scratch may now overlap it

    #pragma unroll
    for (int oi = 0; oi < 4; ++oi)
        #pragma unroll
        for (int qi = 0; qi < 8; ++qi)
            scratch[(jc * 128 + og * 4 + oi) * 9 + qi] = acc2[oi][qi];
    __syncthreads();

    // ---------------- final reduce over jc + normalize + store -----------------
    {
        const int o  = tid & 127;
        const int qg = tid >> 7;
        #pragma unroll
        for (int i = 0; i < 4; ++i) {
            int q = qg * 4 + i;
            float s = 0.f;
            #pragma unroll
            for (int jc2 = 0; jc2 < 8; ++jc2)
                s += scratch[(jc2 * 128 + o) * 9 + q];
            int gq = q0 + q;
            if (gq < N) {
                float nn = (float)max(cnt[q], 1);
                out[gq * COUT + o] = s / nn;
            }
        }
    }
}

extern "C" void kernel_launch(void* const* d_in, const int* in_sizes, int n_in,
                              void* d_out, int out_size, void* d_ws, size_t ws_size,
                              hipStream_t stream) {
    const float* q_pts  = (const float*)d_in[0];
    const float* s_pts  = (const float*)d_in[1];
    const int*   nbinds = (const int*)d_in[2];
    const float* x      = (const float*)d_in[3];
    const float* kp     = (const float*)d_in[4];
    const float* wmat   = (const float*)d_in[5];
    float* out = (float*)d_out;
    int N = in_sizes[0] / 3;
    int M = in_sizes[1] / 3;

    float* rowsum = (float*)d_ws;   // M floats

    int rb = (M + 3) / 4;
    rowsum_kernel<<<rb, 256, 0, stream>>>(x, rowsum, M);

    int mb = (N + QB - 1) / QB;
    kpconv_main<<<mb, 256, 0, stream>>>(q_pts, s_pts, nbinds, x, kp, wmat,
                                        rowsum, out, N, M);
}

// Round 2
// 231.450 us; speedup vs baseline: 1.7240x; 1.7240x over previous
//
#include <hip/hip_runtime.h>
#include <math.h>

// KPConv fused kernel for MI355X (gfx950), round 2: bf16 MFMA Phase C.
// Shapes: N=50000, M=50000, H=40, K=15, CIN=64, COUT=128.
typedef unsigned short ushort_t;
typedef __attribute__((ext_vector_type(8))) short bf16x8;   // 8 bf16 = 4 VGPRs
typedef __attribute__((ext_vector_type(4))) float f32x4;

constexpr int H    = 40;
constexpr int KKP  = 15;
constexpr int CIN  = 64;
constexpr int COUT = 128;
constexpr int QB   = 8;          // queries per block
constexpr int NP   = QB * H;     // 320 (q,h) pairs per block
constexpr int S2   = 328;        // w_s row stride (320 + pad)
constexpr int SWF  = 968;        // WF row stride in bf16 elems (960+8; *2B=1936, 16B-aligned)
constexpr float INV_KPE = 1.0f / 1.2f;

__device__ inline ushort_t f2bf(float f) {   // fp32 -> bf16 RNE
    union { float f; unsigned u; } v; v.f = f;
    unsigned r = v.u + 0x7FFFu + ((v.u >> 16) & 1u);
    return (ushort_t)(r >> 16);
}

// ---------------- kernel 1: per-support-row feature sums (UNCHANGED) ----------
__global__ __launch_bounds__(256) void rowsum_kernel(const float* __restrict__ x,
                                                     float* __restrict__ rowsum, int M) {
    int row  = blockIdx.x * 4 + (threadIdx.x >> 6);
    int lane = threadIdx.x & 63;
    if (row >= M) return;
    float v = x[row * CIN + lane];   // CIN == 64 == wave width
    #pragma unroll
    for (int off = 32; off > 0; off >>= 1) v += __shfl_down(v, off, 64);
    if (lane == 0) rowsum[row] = v;
}

// ---------------- kernel 2: W -> bf16 MFMA-fragment order ----------------------
// wb[((jt*8 + ot)*64 + lane)*8 + r] = bf16( W[jt*32 + (lane>>4)*8 + r][ot*16 + (lane&15)] )
// Same k-grouping assumption as the A-fragment load below => any k-permutation cancels.
__global__ __launch_bounds__(256) void wprep_kernel(const float* __restrict__ wmat,
                                                    ushort_t* __restrict__ wb) {
    int t = blockIdx.x * 256 + threadIdx.x;
    if (t >= 30 * 8 * 64) return;
    int lane = t & 63;
    int ot   = (t >> 6) & 7;
    int jt   = t >> 9;
    int o  = ot * 16 + (lane & 15);
    int kb = jt * 32 + (lane >> 4) * 8;
    unsigned pk[4];
    #pragma unroll
    for (int r = 0; r < 4; ++r) {
        unsigned lo = f2bf(wmat[(kb + 2 * r) * COUT + o]);
        unsigned hi = f2bf(wmat[(kb + 2 * r + 1) * COUT + o]);
        pk[r] = lo | (hi << 16);
    }
    *(uint4*)&wb[(size_t)t * 8] = make_uint4(pk[0], pk[1], pk[2], pk[3]);
}

// ---------------- kernel 3: fused KPConv --------------------------------------
// LDS: w_s 19680 + wmax 1280 + inds 1280 + cnt 32 + WF16 15488 = 37760 B -> 4 blocks/CU
__global__ __launch_bounds__(256, 4) void kpconv_main(
    const float* __restrict__ q_pts, const float* __restrict__ s_pts,
    const int*   __restrict__ nbinds, const float* __restrict__ x,
    const float* __restrict__ kp,     const ushort_t* __restrict__ wb,
    const float* __restrict__ rowsum, float* __restrict__ out,
    int N, int M)
{
    __shared__ float    w_s[KKP * S2];     // [k][p], stride-1 lane writes: conflict-free
    __shared__ float    wmax_s[NP];
    __shared__ int      inds_s[NP];
    __shared__ int      cnt[QB];
    __shared__ __align__(16) ushort_t WF16[QB * SWF];   // bf16 WF, [q][j]

    const int tid = threadIdx.x;
    const int q0  = blockIdx.x * QB;

    if (tid < QB) cnt[tid] = 0;
    __syncthreads();

    // ---------------- Phase A: KP influence weights + validity -----------------
    for (int p = tid; p < NP; p += 256) {
        int q  = p / H;
        int h  = p - q * H;
        int gq = q0 + q;
        int ind = nbinds[gq * H + h];
        inds_s[p] = ind;
        float nx = 0.f, ny = 0.f, nz = 0.f;
        bool shadow = (ind >= M);
        if (!shadow) {
            nx = s_pts[ind * 3 + 0] - q_pts[gq * 3 + 0];
            ny = s_pts[ind * 3 + 1] - q_pts[gq * 3 + 1];
            nz = s_pts[ind * 3 + 2] - q_pts[gq * 3 + 2];
            if (rowsum[ind] > 0.0f) atomicAdd(&cnt[q], 1);
        }
        float n2 = nx * nx + ny * ny + nz * nz;
        float wmax = 0.f;
        #pragma unroll
        for (int k = 0; k < KKP; ++k) {
            float wv = 0.f;
            if (!shadow) {
                float kx = kp[k * 3 + 0], ky = kp[k * 3 + 1], kz = kp[k * 3 + 2];
                float k2 = kx * kx + ky * ky + kz * kz;
                float cross = nx * kx + ny * ky + nz * kz;
                float sq = fmaxf(n2 + k2 - 2.0f * cross, 0.0f);
                wv = fmaxf(1.0f - sqrtf(sq) * INV_KPE, 0.0f);
            }
            w_s[k * S2 + p] = wv;
            wmax = fmaxf(wmax, wv);
        }
        wmax_s[p] = wmax;
    }
    __syncthreads();

    // ---------------- Phase B: WF[q][k*64+c] accumulation (fp32 -> bf16) -------
    const int wid = tid >> 6;   // wave id 0..3
    const int c   = tid & 63;
    for (int r = 0; r < 2; ++r) {
        int q  = r * 4 + wid;
        int pb = q * H;
        float acc[KKP];
        #pragma unroll
        for (int k = 0; k < KKP; ++k) acc[k] = 0.f;
        for (int h = 0; h < H; ++h) {
            // wave-uniform skip: all lanes read the same wmax -> scalar branch
            float wm = __uint_as_float(
                __builtin_amdgcn_readfirstlane(__float_as_uint(wmax_s[pb + h])));
            if (wm > 0.f) {
                int ind = __builtin_amdgcn_readfirstlane(inds_s[pb + h]);
                float xv = x[ind * CIN + c];   // coalesced 256B gather
                #pragma unroll
                for (int k = 0; k < KKP; ++k)
                    acc[k] += w_s[k * S2 + pb + h] * xv;   // broadcast LDS reads
            }
        }
        #pragma unroll
        for (int k = 0; k < KKP; ++k)
            WF16[q * SWF + k * 64 + c] = f2bf(acc[k]);     // stride-1 b16 writes
    }
    __syncthreads();

    // ---------------- Phase C: out[q][o] via MFMA ------------------------------
    // A = WF (16 rows: q = row&7, rows 8..15 duplicate), B = wb fragments.
    // A-frag: lane holds WF[(lane&15)&7][jt*32 + (lane>>4)*8 + i], i=0..7 (1x b128)
    const int lane = tid & 63;
    const int qrow = lane & 7;
    const int kg   = lane >> 4;
    const int ot0  = wid * 2;          // this wave's two 16-col output tiles
    f32x4 acc0 = {0.f, 0.f, 0.f, 0.f};
    f32x4 acc1 = {0.f, 0.f, 0.f, 0.f};
    const ushort_t* wfrow = &WF16[qrow * SWF + kg * 8];
    const ushort_t* bbase = wb + ((size_t)(ot0 * 64 + lane)) * 8;
    for (int jt = 0; jt < 30; ++jt) {
        bf16x8 a  = *(const bf16x8*)&wfrow[jt * 32];
        bf16x8 b0 = *(const bf16x8*)&bbase[(size_t)jt * 8 * 64 * 8];
        bf16x8 b1 = *(const bf16x8*)&bbase[(size_t)jt * 8 * 64 * 8 + 64 * 8];
        acc0 = __builtin_amdgcn_mfma_f32_16x16x32_bf16(a, b0, acc0, 0, 0, 0);
        acc1 = __builtin_amdgcn_mfma_f32_16x16x32_bf16(a, b1, acc1, 0, 0, 0);
    }

    // C/D layout (guide-verified): col = lane&15, row = (lane>>4)*4 + reg.
    // Rows 0..7 are the 8 real queries; lanes 32..63 hold duplicates -> skip.
    if (lane < 32) {
        int col = ot0 * 16 + (lane & 15);
        #pragma unroll
        for (int reg = 0; reg < 4; ++reg) {
            int row = (lane >> 4) * 4 + reg;
            float inv = 1.0f / (float)max(cnt[row], 1);
            int gq = q0 + row;
            if (gq < N) {
                out[(size_t)gq * COUT + col]      = acc0[reg] * inv;
                out[(size_t)gq * COUT + col + 16] = acc1[reg] * inv;
            }
        }
    }
}

extern "C" void kernel_launch(void* const* d_in, const int* in_sizes, int n_in,
                              void* d_out, int out_size, void* d_ws, size_t ws_size,
                              hipStream_t stream) {
    const float* q_pts  = (const float*)d_in[0];
    const float* s_pts  = (const float*)d_in[1];
    const int*   nbinds = (const int*)d_in[2];
    const float* x      = (const float*)d_in[3];
    const float* kp     = (const float*)d_in[4];
    const float* wmat   = (const float*)d_in[5];
    float* out = (float*)d_out;
    int N = in_sizes[0] / 3;
    int M = in_sizes[1] / 3;

    float*    rowsum = (float*)d_ws;                                   // M floats
    size_t    wboff  = ((size_t)M * 4 + 255) & ~(size_t)255;           // 16B-aligned
    ushort_t* wb     = (ushort_t*)((char*)d_ws + wboff);               // 245760 B

    rowsum_kernel<<<(M + 3) / 4, 256, 0, stream>>>(x, rowsum, M);
    wprep_kernel<<<60, 256, 0, stream>>>(wmat, wb);
    kpconv_main<<<(N + QB - 1) / QB, 256, 0, stream>>>(q_pts, s_pts, nbinds, x, kp,
                                                       wb, rowsum, out, N, M);
}

// Round 3
// 150.217 us; speedup vs baseline: 2.6563x; 1.5408x over previous
//
#include <hip/hip_runtime.h>
#include <math.h>

// KPConv fused kernel for MI355X (gfx950), round 3: compacted + pipelined gather.
// Shapes: N=50000, M=50000, H=40, K=15, CIN=64, COUT=128.
typedef unsigned short ushort_t;
typedef __attribute__((ext_vector_type(8))) short bf16x8;   // 8 bf16 = 4 VGPRs
typedef __attribute__((ext_vector_type(4))) float f32x4;

constexpr int H    = 40;
constexpr int KKP  = 15;
constexpr int CIN  = 64;
constexpr int COUT = 128;
constexpr int QB   = 8;          // queries per block
constexpr int NP   = QB * H;     // 320 (q,h) pairs per block
constexpr int SWF  = 968;        // WF row stride in bf16 elems (960+8; *2B=1936, 16B-aligned)
constexpr float INV_KPE = 1.0f / 1.2f;

__device__ inline ushort_t f2bf(float f) {   // fp32 -> bf16 RNE
    union { float f; unsigned u; } v; v.f = f;
    unsigned r = v.u + 0x7FFFu + ((v.u >> 16) & 1u);
    return (ushort_t)(r >> 16);
}
__device__ inline float bf2f(ushort_t u) {
    return __uint_as_float(((unsigned)u) << 16);
}

// ---- kernel 1: per-support-row feature sums (reduction order UNCHANGED) + bf16 x copy
__global__ __launch_bounds__(256) void prep_kernel(const float* __restrict__ x,
                                                   float* __restrict__ rowsum,
                                                   ushort_t* __restrict__ xb,
                                                   int M, int write_xb) {
    int row  = blockIdx.x * 4 + (threadIdx.x >> 6);
    int lane = threadIdx.x & 63;
    if (row >= M) return;
    float v = x[row * CIN + lane];   // CIN == 64 == wave width
    if (write_xb) xb[row * CIN + lane] = f2bf(v);
    #pragma unroll
    for (int off = 32; off > 0; off >>= 1) v += __shfl_down(v, off, 64);
    if (lane == 0) rowsum[row] = v;
}

// ---- kernel 2: W -> bf16 MFMA-fragment order (UNCHANGED from R2, passed) ------
__global__ __launch_bounds__(256) void wprep_kernel(const float* __restrict__ wmat,
                                                    ushort_t* __restrict__ wb) {
    int t = blockIdx.x * 256 + threadIdx.x;
    if (t >= 30 * 8 * 64) return;
    int lane = t & 63;
    int ot   = (t >> 6) & 7;
    int jt   = t >> 9;
    int o  = ot * 16 + (lane & 15);
    int kb = jt * 32 + (lane >> 4) * 8;
    unsigned pk[4];
    #pragma unroll
    for (int r = 0; r < 4; ++r) {
        unsigned lo = f2bf(wmat[(kb + 2 * r) * COUT + o]);
        unsigned hi = f2bf(wmat[(kb + 2 * r + 1) * COUT + o]);
        pk[r] = lo | (hi << 16);
    }
    *(uint4*)&wb[(size_t)t * 8] = make_uint4(pk[0], pk[1], pk[2], pk[3]);
}

// ---- kernel 3: fused KPConv ---------------------------------------------------
// LDS: w_p 20480 + cind 1280 + cp 640 + qcnt 32 + cnt 32 + WF16 15488 = 37952 B
//   -> 4 blocks/CU (16 waves).
template<bool BF16X>
__global__ __launch_bounds__(256, 4) void kpconv_main(
    const float* __restrict__ q_pts, const float* __restrict__ s_pts,
    const int*   __restrict__ nbinds, const float* __restrict__ xf,
    const ushort_t* __restrict__ xb,  const float* __restrict__ kp,
    const ushort_t* __restrict__ wb,  const float* __restrict__ rowsum,
    float* __restrict__ out, int N, int M)
{
    __shared__ __align__(16) float    w_p[NP * 16];   // [p][16] (15 + pad), active rows only
    __shared__ int      cind[NP];                     // [q][slot] -> support row index
    __shared__ ushort_t cp[NP];                       // [q][slot] -> p (w_p row)
    __shared__ int      qcnt[QB];                     // active slots per q
    __shared__ int      cnt[QB];                      // valid-neighbor count (normalizer)
    __shared__ __align__(16) ushort_t WF16[QB * SWF]; // bf16 WF, [q][j]

    const int tid = threadIdx.x;
    const int q0  = blockIdx.x * QB;

    if (tid < QB) { qcnt[tid] = 0; cnt[tid] = 0; }
    __syncthreads();

    // ---------------- Phase A: KP weights + validity + compaction --------------
    for (int p = tid; p < NP; p += 256) {
        int q  = p / H;
        int h  = p - q * H;
        int gq = q0 + q;
        int ind = nbinds[gq * H + h];
        bool shadow = (ind >= M);
        float nx = 0.f, ny = 0.f, nz = 0.f;
        if (!shadow) {
            nx = s_pts[ind * 3 + 0] - q_pts[gq * 3 + 0];
            ny = s_pts[ind * 3 + 1] - q_pts[gq * 3 + 1];
            nz = s_pts[ind * 3 + 2] - q_pts[gq * 3 + 2];
            if (rowsum[ind] > 0.0f) atomicAdd(&cnt[q], 1);
        }
        float n2 = nx * nx + ny * ny + nz * nz;
        float w[16];
        float wmax = 0.f;
        #pragma unroll
        for (int k = 0; k < KKP; ++k) {
            float wv = 0.f;
            if (!shadow) {
                float kx = kp[k * 3 + 0], ky = kp[k * 3 + 1], kz = kp[k * 3 + 2];
                float k2 = kx * kx + ky * ky + kz * kz;
                float cross = nx * kx + ny * ky + nz * kz;
                float sq = fmaxf(n2 + k2 - 2.0f * cross, 0.0f);
                wv = fmaxf(1.0f - sqrtf(sq) * INV_KPE, 0.0f);
            }
            w[k] = wv;
            wmax = fmaxf(wmax, wv);
        }
        w[15] = 0.f;
        if (wmax > 0.f) {
            int slot = atomicAdd(&qcnt[q], 1);
            cind[q * H + slot] = ind;
            cp[q * H + slot]   = (ushort_t)p;
            float4* dst = (float4*)&w_p[p * 16];
            dst[0] = make_float4(w[0],  w[1],  w[2],  w[3]);
            dst[1] = make_float4(w[4],  w[5],  w[6],  w[7]);
            dst[2] = make_float4(w[8],  w[9],  w[10], w[11]);
            dst[3] = make_float4(w[12], w[13], w[14], w[15]);
        }
    }
    __syncthreads();

    // ---------------- Phase B: WF[q][k*64+c], pipelined compacted gather -------
    const int wid = tid >> 6;   // wave id 0..3
    const int c   = tid & 63;
    constexpr int CH = 8;       // pipeline chunk (loads in flight)
    for (int r = 0; r < 2; ++r) {
        int q  = r * 4 + wid;
        int nc = qcnt[q];       // wave-uniform
        float acc[KKP];
        #pragma unroll
        for (int k = 0; k < KKP; ++k) acc[k] = 0.f;

        if (nc > 0) {
            const int*      ci  = &cind[q * H];
            const ushort_t* cpq = &cp[q * H];
            float xcur[CH], xnxt[CH];
            #pragma unroll
            for (int j = 0; j < CH; ++j) {   // prologue: chunk 0 loads
                int s   = min(j, nc - 1);
                int ind = ci[s];
                xcur[j] = BF16X ? bf2f(xb[(size_t)ind * CIN + c])
                                : xf[(size_t)ind * CIN + c];
            }
            for (int base = 0; base < nc; base += CH) {
                #pragma unroll
                for (int j = 0; j < CH; ++j) {   // prefetch next chunk (clamped)
                    int s   = min(base + CH + j, nc - 1);
                    int ind = ci[s];
                    xnxt[j] = BF16X ? bf2f(xb[(size_t)ind * CIN + c])
                                    : xf[(size_t)ind * CIN + c];
                }
                #pragma unroll
                for (int j = 0; j < CH; ++j) {
                    if (base + j < nc) {         // wave-uniform predicate
                        int p = cpq[base + j];
                        const float4* wr = (const float4*)&w_p[p * 16];
                        float4 w0 = wr[0], w1 = wr[1], w2 = wr[2], w3 = wr[3];
                        float xv = xcur[j];
                        acc[0]  += w0.x * xv; acc[1]  += w0.y * xv;
                        acc[2]  += w0.z * xv; acc[3]  += w0.w * xv;
                        acc[4]  += w1.x * xv; acc[5]  += w1.y * xv;
                        acc[6]  += w1.z * xv; acc[7]  += w1.w * xv;
                        acc[8]  += w2.x * xv; acc[9]  += w2.y * xv;
                        acc[10] += w2.z * xv; acc[11] += w2.w * xv;
                        acc[12] += w3.x * xv; acc[13] += w3.y * xv;
                        acc[14] += w3.z * xv;
                    }
                }
                #pragma unroll
                for (int j = 0; j < CH; ++j) xcur[j] = xnxt[j];
            }
        }
        #pragma unroll
        for (int k = 0; k < KKP; ++k)
            WF16[q * SWF + k * 64 + c] = f2bf(acc[k]);     // stride-1 b16 writes
    }
    __syncthreads();

    // ---------------- Phase C: out[q][o] via MFMA (UNCHANGED from R2) ----------
    const int lane = tid & 63;
    const int qrow = lane & 7;
    const int kg   = lane >> 4;
    const int ot0  = wid * 2;
    f32x4 acc0 = {0.f, 0.f, 0.f, 0.f};
    f32x4 acc1 = {0.f, 0.f, 0.f, 0.f};
    const ushort_t* wfrow = &WF16[qrow * SWF + kg * 8];
    const ushort_t* bbase = wb + ((size_t)(ot0 * 64 + lane)) * 8;
    for (int jt = 0; jt < 30; ++jt) {
        bf16x8 a  = *(const bf16x8*)&wfrow[jt * 32];
        bf16x8 b0 = *(const bf16x8*)&bbase[(size_t)jt * 8 * 64 * 8];
        bf16x8 b1 = *(const bf16x8*)&bbase[(size_t)jt * 8 * 64 * 8 + 64 * 8];
        acc0 = __builtin_amdgcn_mfma_f32_16x16x32_bf16(a, b0, acc0, 0, 0, 0);
        acc1 = __builtin_amdgcn_mfma_f32_16x16x32_bf16(a, b1, acc1, 0, 0, 0);
    }

    // C/D layout: col = lane&15, row = (lane>>4)*4 + reg. Rows 0..7 = queries.
    if (lane < 32) {
        int col = ot0 * 16 + (lane & 15);
        #pragma unroll
        for (int reg = 0; reg < 4; ++reg) {
            int row = (lane >> 4) * 4 + reg;
            float inv = 1.0f / (float)max(cnt[row], 1);
            int gq = q0 + row;
            if (gq < N) {
                out[(size_t)gq * COUT + col]      = acc0[reg] * inv;
                out[(size_t)gq * COUT + col + 16] = acc1[reg] * inv;
            }
        }
    }
}

extern "C" void kernel_launch(void* const* d_in, const int* in_sizes, int n_in,
                              void* d_out, int out_size, void* d_ws, size_t ws_size,
                              hipStream_t stream) {
    const float* q_pts  = (const float*)d_in[0];
    const float* s_pts  = (const float*)d_in[1];
    const int*   nbinds = (const int*)d_in[2];
    const float* x      = (const float*)d_in[3];
    const float* kp     = (const float*)d_in[4];
    const float* wmat   = (const float*)d_in[5];
    float* out = (float*)d_out;
    int N = in_sizes[0] / 3;
    int M = in_sizes[1] / 3;

    // workspace carve: rowsum (M f32) | wb (245760 B) | xb (M*64 bf16)
    size_t    off_wb = ((size_t)M * 4 + 255) & ~(size_t)255;
    size_t    off_xb = (off_wb + 245760 + 255) & ~(size_t)255;
    size_t    need   = off_xb + (size_t)M * CIN * 2;
    float*    rowsum = (float*)d_ws;
    ushort_t* wb     = (ushort_t*)((char*)d_ws + off_wb);
    ushort_t* xb     = (ushort_t*)((char*)d_ws + off_xb);
    bool use_bf16x = (ws_size >= need);

    prep_kernel<<<(M + 3) / 4, 256, 0, stream>>>(x, rowsum, xb, M, use_bf16x ? 1 : 0);
    wprep_kernel<<<60, 256, 0, stream>>>(wmat, wb);
    int mb = (N + QB - 1) / QB;
    if (use_bf16x)
        kpconv_main<true><<<mb, 256, 0, stream>>>(q_pts, s_pts, nbinds, x, xb, kp,
                                                  wb, rowsum, out, N, M);
    else
        kpconv_main<false><<<mb, 256, 0, stream>>>(q_pts, s_pts, nbinds, x, xb, kp,
                                                   wb, rowsum, out, N, M);
}

// Round 5
// 144.211 us; speedup vs baseline: 2.7669x; 1.0416x over previous
//
#include <hip/hip_runtime.h>
#include <math.h>

// KPConv fused, round 5: R3 structure + occupancy (5 blk/CU) + pipelined Phase C.
// Shapes: N=50000, M=50000, H=40, K=15, CIN=64, COUT=128.
typedef unsigned short ushort_t;
typedef __attribute__((ext_vector_type(8))) short bf16x8;   // 8 bf16 = 4 VGPRs
typedef __attribute__((ext_vector_type(4))) float f32x4;

constexpr int H    = 40;
constexpr int KKP  = 15;
constexpr int CIN  = 64;
constexpr int COUT = 128;
constexpr int QB   = 8;          // queries per block
constexpr int NP   = QB * H;     // 320 (q,h) pairs per block
constexpr int SWF  = 984;        // WF16 row stride: 1968 B -> 16B-chunk step 3 mod 8
constexpr float INV_KPE = 1.0f / 1.2f;

__device__ __forceinline__ ushort_t f2bf(float f) {   // fp32 -> bf16 RNE
    union { float f; unsigned u; } v; v.f = f;
    unsigned r = v.u + 0x7FFFu + ((v.u >> 16) & 1u);
    return (ushort_t)(r >> 16);
}
__device__ __forceinline__ float bf2f(ushort_t u) {
    return __uint_as_float(((unsigned)u) << 16);
}
__device__ __forceinline__ float bflo(unsigned u) {   // low bf16 of pair -> f32
    return __uint_as_float(u << 16);
}
__device__ __forceinline__ float bfhi(unsigned u) {   // high bf16 of pair -> f32
    return __uint_as_float(u & 0xffff0000u);
}

// ---- kernel 1: per-support-row feature sums (reduction order UNCHANGED) + bf16 x copy
__global__ __launch_bounds__(256) void prep_kernel(const float* __restrict__ x,
                                                   float* __restrict__ rowsum,
                                                   ushort_t* __restrict__ xb,
                                                   int M, int write_xb) {
    int row  = blockIdx.x * 4 + (threadIdx.x >> 6);
    int lane = threadIdx.x & 63;
    if (row >= M) return;
    float v = x[row * CIN + lane];   // CIN == 64 == wave width
    if (write_xb) xb[row * CIN + lane] = f2bf(v);
    #pragma unroll
    for (int off = 32; off > 0; off >>= 1) v += __shfl_down(v, off, 64);
    if (lane == 0) rowsum[row] = v;
}

// ---- kernel 2: W -> bf16 MFMA-fragment order (UNCHANGED, validated R2/R3) ----
__global__ __launch_bounds__(256) void wprep_kernel(const float* __restrict__ wmat,
                                                    ushort_t* __restrict__ wb) {
    int t = blockIdx.x * 256 + threadIdx.x;
    if (t >= 30 * 8 * 64) return;
    int lane = t & 63;
    int ot   = (t >> 6) & 7;
    int jt   = t >> 9;
    int o  = ot * 16 + (lane & 15);
    int kb = jt * 32 + (lane >> 4) * 8;
    unsigned pk[4];
    #pragma unroll
    for (int r = 0; r < 4; ++r) {
        unsigned lo = f2bf(wmat[(kb + 2 * r) * COUT + o]);
        unsigned hi = f2bf(wmat[(kb + 2 * r + 1) * COUT + o]);
        pk[r] = lo | (hi << 16);
    }
    *(uint4*)&wb[(size_t)t * 8] = make_uint4(pk[0], pk[1], pk[2], pk[3]);
}

// ---- kernel 3: fused KPConv ---------------------------------------------------
// LDS: w_pk 10240 + cind 1280 + qcnt 32 + cnt 32 + WF16 15744 = 27328 B -> 5 blk/CU
template<bool BF16X>
__global__ __launch_bounds__(256, 5) void kpconv_main(
    const float* __restrict__ q_pts, const float* __restrict__ s_pts,
    const int*   __restrict__ nbinds, const float* __restrict__ xf,
    const ushort_t* __restrict__ xb,  const float* __restrict__ kp,
    const ushort_t* __restrict__ wb,  const float* __restrict__ rowsum,
    float* __restrict__ out, int N, int M)
{
    __shared__ __align__(16) unsigned w_pk[NP * 8];   // [slot-row][8]: 16 bf16 (15 + pad)
    __shared__ int      cind[NP];                     // [q][slot] -> support row index
    __shared__ int      qcnt[QB];                     // active slots per q
    __shared__ int      cnt[QB];                      // valid-neighbor count (normalizer)
    __shared__ __align__(16) ushort_t WF16[QB * SWF]; // bf16 WF, [q][j], padded stride

    const int tid = threadIdx.x;
    const int q0  = blockIdx.x * QB;

    if (tid < QB) { qcnt[tid] = 0; cnt[tid] = 0; }
    __syncthreads();

    // ---------------- Phase A: KP weights + validity + compaction --------------
    for (int p = tid; p < NP; p += 256) {
        int q  = p / H;
        int h  = p - q * H;
        int gq = q0 + q;
        int ind = nbinds[gq * H + h];
        bool shadow = (ind >= M);
        float nx = 0.f, ny = 0.f, nz = 0.f;
        if (!shadow) {
            nx = s_pts[ind * 3 + 0] - q_pts[gq * 3 + 0];
            ny = s_pts[ind * 3 + 1] - q_pts[gq * 3 + 1];
            nz = s_pts[ind * 3 + 2] - q_pts[gq * 3 + 2];
            if (rowsum[ind] > 0.0f) atomicAdd(&cnt[q], 1);
        }
        float n2 = nx * nx + ny * ny + nz * nz;
        float w[16];
        float wmax = 0.f;
        #pragma unroll
        for (int k = 0; k < KKP; ++k) {
            float wv = 0.f;
            if (!shadow) {
                float kx = kp[k * 3 + 0], ky = kp[k * 3 + 1], kz = kp[k * 3 + 2];
                float k2 = kx * kx + ky * ky + kz * kz;
                float cross = nx * kx + ny * ky + nz * kz;
                float sq = fmaxf(n2 + k2 - 2.0f * cross, 0.0f);
                wv = fmaxf(1.0f - sqrtf(sq) * INV_KPE, 0.0f);
            }
            w[k] = wv;
            wmax = fmaxf(wmax, wv);
        }
        w[15] = 0.f;
        if (wmax > 0.f) {
            int slot = atomicAdd(&qcnt[q], 1);
            int row  = q * H + slot;          // slot-compacted w row
            cind[row] = ind;
            unsigned pk[8];
            #pragma unroll
            for (int i = 0; i < 8; ++i)
                pk[i] = (unsigned)f2bf(w[2 * i]) | ((unsigned)f2bf(w[2 * i + 1]) << 16);
            uint4* dst = (uint4*)&w_pk[row * 8];
            dst[0] = make_uint4(pk[0], pk[1], pk[2], pk[3]);
            dst[1] = make_uint4(pk[4], pk[5], pk[6], pk[7]);
        }
    }
    __syncthreads();

    // ---------------- Phase B: WF[q][k*64+c], pipelined compacted gather -------
    const int wid = tid >> 6;   // wave id 0..3
    const int c   = tid & 63;
    constexpr int CH = 8;       // gather pipeline depth
    for (int r = 0; r < 2; ++r) {
        int q  = r * 4 + wid;
        int nc = qcnt[q];       // wave-uniform
        int qH = q * H;
        float acc[KKP];
        #pragma unroll
        for (int k = 0; k < KKP; ++k) acc[k] = 0.f;

        if (nc > 0) {
            float xcur[CH], xnxt[CH];
            #pragma unroll
            for (int j = 0; j < CH; ++j) {   // prologue: chunk 0 loads
                int ind = cind[qH + min(j, nc - 1)];
                xcur[j] = BF16X ? bf2f(xb[(size_t)ind * CIN + c])
                                : xf[(size_t)ind * CIN + c];
            }
            for (int base = 0; base < nc; base += CH) {
                #pragma unroll
                for (int j = 0; j < CH; ++j) {   // prefetch next chunk (clamped)
                    int ind = cind[qH + min(base + CH + j, nc - 1)];
                    xnxt[j] = BF16X ? bf2f(xb[(size_t)ind * CIN + c])
                                    : xf[(size_t)ind * CIN + c];
                }
                #pragma unroll
                for (int j = 0; j < CH; ++j) {
                    if (base + j < nc) {         // wave-uniform predicate
                        const uint4* wr = (const uint4*)&w_pk[(qH + base + j) * 8];
                        uint4 pa = wr[0], pb = wr[1];    // broadcast LDS reads
                        float xv = xcur[j];
                        acc[0]  += bflo(pa.x) * xv; acc[1]  += bfhi(pa.x) * xv;
                        acc[2]  += bflo(pa.y) * xv; acc[3]  += bfhi(pa.y) * xv;
                        acc[4]  += bflo(pa.z) * xv; acc[5]  += bfhi(pa.z) * xv;
                        acc[6]  += bflo(pa.w) * xv; acc[7]  += bfhi(pa.w) * xv;
                        acc[8]  += bflo(pb.x) * xv; acc[9]  += bfhi(pb.x) * xv;
                        acc[10] += bflo(pb.y) * xv; acc[11] += bfhi(pb.y) * xv;
                        acc[12] += bflo(pb.z) * xv; acc[13] += bfhi(pb.z) * xv;
                        acc[14] += bflo(pb.w) * xv;
                    }
                }
                #pragma unroll
                for (int j = 0; j < CH; ++j) xcur[j] = xnxt[j];
            }
        }
        #pragma unroll
        for (int k = 0; k < KKP; ++k)
            WF16[q * SWF + k * 64 + c] = f2bf(acc[k]);     // stride-1 b16 writes
    }
    __syncthreads();

    // ---------------- Phase C: out[q][o] via MFMA, 6-deep wb prefetch ----------
    {
        const int lane = tid & 63;
        const int qrow = lane & 7;
        const int kg   = lane >> 4;
        const int ot0  = wid * 2;
        f32x4 c0 = {0.f,0.f,0.f,0.f}, c1 = {0.f,0.f,0.f,0.f};
        const ushort_t* wfrow = &WF16[qrow * SWF + kg * 8];
        const ushort_t* bbase = wb + ((size_t)(ot0 * 64 + lane)) * 8;

        bf16x8 rb0[6], rb1[6];
        #pragma unroll
        for (int i = 0; i < 6; ++i) {        // preload jt = 0..5
            rb0[i] = *(const bf16x8*)&bbase[(size_t)i * 4096];
            rb1[i] = *(const bf16x8*)&bbase[(size_t)i * 4096 + 512];
        }
        for (int m = 0; m < 5; ++m) {        // 5 x 6 = 30 jt steps
            #pragma unroll
            for (int u = 0; u < 6; ++u) {
                int jt = m * 6 + u;
                bf16x8 a = *(const bf16x8*)&wfrow[jt * 32];
                c0 = __builtin_amdgcn_mfma_f32_16x16x32_bf16(a, rb0[u], c0, 0, 0, 0);
                c1 = __builtin_amdgcn_mfma_f32_16x16x32_bf16(a, rb1[u], c1, 0, 0, 0);
                if (m < 4) {                 // prefetch jt+6 into freed slot
                    rb0[u] = *(const bf16x8*)&bbase[(size_t)(jt + 6) * 4096];
                    rb1[u] = *(const bf16x8*)&bbase[(size_t)(jt + 6) * 4096 + 512];
                }
            }
        }

        // C/D layout: col = lane&15, row = (lane>>4)*4 + reg. Rows 0..7 = queries.
        if (lane < 32) {
            int col = ot0 * 16 + (lane & 15);
            #pragma unroll
            for (int reg = 0; reg < 4; ++reg) {
                int row = (lane >> 4) * 4 + reg;
                float inv = 1.0f / (float)max(cnt[row], 1);
                int gq = q0 + row;
                if (gq < N) {
                    out[(size_t)gq * COUT + col]      = c0[reg] * inv;
                    out[(size_t)gq * COUT + col + 16] = c1[reg] * inv;
                }
            }
        }
    }
}

extern "C" void kernel_launch(void* const* d_in, const int* in_sizes, int n_in,
                              void* d_out, int out_size, void* d_ws, size_t ws_size,
                              hipStream_t stream) {
    const float* q_pts  = (const float*)d_in[0];
    const float* s_pts  = (const float*)d_in[1];
    const int*   nbinds = (const int*)d_in[2];
    const float* x      = (const float*)d_in[3];
    const float* kp     = (const float*)d_in[4];
    const float* wmat   = (const float*)d_in[5];
    float* out = (float*)d_out;
    int N = in_sizes[0] / 3;
    int M = in_sizes[1] / 3;

    // workspace carve: rowsum (M f32) | wb (245760 B) | xb (M*64 bf16)
    size_t    off_wb = ((size_t)M * 4 + 255) & ~(size_t)255;
    size_t    off_xb = (off_wb + 245760 + 255) & ~(size_t)255;
    size_t    need   = off_xb + (size_t)M * CIN * 2;
    float*    rowsum = (float*)d_ws;
    ushort_t* wb     = (ushort_t*)((char*)d_ws + off_wb);
    ushort_t* xb     = (ushort_t*)((char*)d_ws + off_xb);
    bool use_bf16x = (ws_size >= need);

    prep_kernel<<<(M + 3) / 4, 256, 0, stream>>>(x, rowsum, xb, M, use_bf16x ? 1 : 0);
    wprep_kernel<<<60, 256, 0, stream>>>(wmat, wb);
    int mb = (N + QB - 1) / QB;
    if (use_bf16x)
        kpconv_main<true><<<mb, 256, 0, stream>>>(q_pts, s_pts, nbinds, x, xb, kp,
                                                  wb, rowsum, out, N, M);
    else
        kpconv_main<false><<<mb, 256, 0, stream>>>(q_pts, s_pts, nbinds, x, xb, kp,
                                                   wb, rowsum, out, N, M);
}

// Round 8
// 139.739 us; speedup vs baseline: 2.8554x; 1.0320x over previous
//
#include <hip/hip_runtime.h>
#include <math.h>

// KPConv fused, round 8: exact R5 structure, ONE isolated change — w stored f32
// (kills the 15-unpack-per-slot VALU tax). All other numerics byte-identical R5.
// Shapes: N=50000, M=50000, H=40, K=15, CIN=64, COUT=128.
typedef unsigned short ushort_t;
typedef __attribute__((ext_vector_type(8))) short bf16x8;   // 8 bf16 = 4 VGPRs
typedef __attribute__((ext_vector_type(4))) float f32x4;

constexpr int H    = 40;
constexpr int KKP  = 15;
constexpr int CIN  = 64;
constexpr int COUT = 128;
constexpr int QB   = 8;          // queries per block
constexpr int NP   = QB * H;     // 320 (q,h) pairs per block
constexpr int SWF  = 984;        // WF16 row stride: 1968 B (16B-aligned, step 3 mod 8)
constexpr float INV_KPE = 1.0f / 1.2f;

__device__ __forceinline__ ushort_t f2bf(float f) {   // fp32 -> bf16 RNE
    union { float f; unsigned u; } v; v.f = f;
    unsigned r = v.u + 0x7FFFu + ((v.u >> 16) & 1u);
    return (ushort_t)(r >> 16);
}
__device__ __forceinline__ float bf2f(ushort_t u) {
    return __uint_as_float(((unsigned)u) << 16);
}

// ---- kernel 1: per-support-row feature sums (reduction order UNCHANGED) + bf16 x copy
__global__ __launch_bounds__(256) void prep_kernel(const float* __restrict__ x,
                                                   float* __restrict__ rowsum,
                                                   ushort_t* __restrict__ xb,
                                                   int M, int write_xb) {
    int row  = blockIdx.x * 4 + (threadIdx.x >> 6);
    int lane = threadIdx.x & 63;
    if (row >= M) return;
    float v = x[row * CIN + lane];   // CIN == 64 == wave width
    if (write_xb) xb[row * CIN + lane] = f2bf(v);
    #pragma unroll
    for (int off = 32; off > 0; off >>= 1) v += __shfl_down(v, off, 64);
    if (lane == 0) rowsum[row] = v;
}

// ---- kernel 2: W -> bf16 MFMA-fragment order (UNCHANGED, validated R2/R3/R5) --
__global__ __launch_bounds__(256) void wprep_kernel(const float* __restrict__ wmat,
                                                    ushort_t* __restrict__ wb) {
    int t = blockIdx.x * 256 + threadIdx.x;
    if (t >= 30 * 8 * 64) return;
    int lane = t & 63;
    int ot   = (t >> 6) & 7;
    int jt   = t >> 9;
    int o  = ot * 16 + (lane & 15);
    int kb = jt * 32 + (lane >> 4) * 8;
    unsigned pk[4];
    #pragma unroll
    for (int r = 0; r < 4; ++r) {
        unsigned lo = f2bf(wmat[(kb + 2 * r) * COUT + o]);
        unsigned hi = f2bf(wmat[(kb + 2 * r + 1) * COUT + o]);
        pk[r] = lo | (hi << 16);
    }
    *(uint4*)&wb[(size_t)t * 8] = make_uint4(pk[0], pk[1], pk[2], pk[3]);
}

// ---- kernel 3: fused KPConv ---------------------------------------------------
// LDS: w_p 20480 + cind 1280 + qcnt 32 + cnt 32 + WF16 15744 = 37568 B -> 4 blk/CU
template<bool BF16X>
__global__ __launch_bounds__(256, 4) void kpconv_main(
    const float* __restrict__ q_pts, const float* __restrict__ s_pts,
    const int*   __restrict__ nbinds, const float* __restrict__ xf,
    const ushort_t* __restrict__ xb,  const float* __restrict__ kp,
    const ushort_t* __restrict__ wb,  const float* __restrict__ rowsum,
    float* __restrict__ out, int N, int M)
{
    __shared__ __align__(16) float w_p[NP * 16];      // [slot-row][16] f32 (15 + pad)
    __shared__ int      cind[NP];                     // [q][slot] -> support row index
    __shared__ int      qcnt[QB];                     // active slots per q
    __shared__ int      cnt[QB];                      // valid-neighbor count (normalizer)
    __shared__ __align__(16) ushort_t WF16[QB * SWF]; // bf16 WF, [q][j], padded stride

    const int tid = threadIdx.x;
    const int q0  = blockIdx.x * QB;

    if (tid < QB) { qcnt[tid] = 0; cnt[tid] = 0; }
    __syncthreads();

    // ---------------- Phase A: KP weights + validity + compaction --------------
    // (byte-identical math to R5: per-k kp loads, sqrtf, same count logic)
    for (int p = tid; p < NP; p += 256) {
        int q  = p / H;
        int h  = p - q * H;
        int gq = q0 + q;
        int ind = nbinds[gq * H + h];
        bool shadow = (ind >= M);
        float nx = 0.f, ny = 0.f, nz = 0.f;
        if (!shadow) {
            nx = s_pts[ind * 3 + 0] - q_pts[gq * 3 + 0];
            ny = s_pts[ind * 3 + 1] - q_pts[gq * 3 + 1];
            nz = s_pts[ind * 3 + 2] - q_pts[gq * 3 + 2];
            if (rowsum[ind] > 0.0f) atomicAdd(&cnt[q], 1);
        }
        float n2 = nx * nx + ny * ny + nz * nz;
        float w[16];
        float wmax = 0.f;
        #pragma unroll
        for (int k = 0; k < KKP; ++k) {
            float wv = 0.f;
            if (!shadow) {
                float kx = kp[k * 3 + 0], ky = kp[k * 3 + 1], kz = kp[k * 3 + 2];
                float k2 = kx * kx + ky * ky + kz * kz;
                float cross = nx * kx + ny * ky + nz * kz;
                float sq = fmaxf(n2 + k2 - 2.0f * cross, 0.0f);
                wv = fmaxf(1.0f - sqrtf(sq) * INV_KPE, 0.0f);
            }
            w[k] = wv;
            wmax = fmaxf(wmax, wv);
        }
        w[15] = 0.f;
        if (wmax > 0.f) {
            int slot = atomicAdd(&qcnt[q], 1);
            int row  = q * H + slot;          // slot-compacted w row
            cind[row] = ind;
            f32x4* dst = (f32x4*)&w_p[row * 16];
            dst[0] = (f32x4){w[0],  w[1],  w[2],  w[3]};
            dst[1] = (f32x4){w[4],  w[5],  w[6],  w[7]};
            dst[2] = (f32x4){w[8],  w[9],  w[10], w[11]};
            dst[3] = (f32x4){w[12], w[13], w[14], w[15]};
        }
    }
    __syncthreads();

    // ---------------- Phase B: WF[q][k*64+c], pipelined compacted gather -------
    const int wid = tid >> 6;   // wave id 0..3
    const int c   = tid & 63;
    constexpr int CH = 8;       // gather pipeline depth
    for (int r = 0; r < 2; ++r) {
        int q  = r * 4 + wid;
        int nc = qcnt[q];       // wave-uniform
        int qH = q * H;
        float acc[KKP];
        #pragma unroll
        for (int k = 0; k < KKP; ++k) acc[k] = 0.f;

        if (nc > 0) {
            float xcur[CH], xnxt[CH];
            #pragma unroll
            for (int j = 0; j < CH; ++j) {   // prologue: chunk 0 loads
                int ind = cind[qH + min(j, nc - 1)];
                xcur[j] = BF16X ? bf2f(xb[(size_t)ind * CIN + c])
                                : xf[(size_t)ind * CIN + c];
            }
            for (int base = 0; base < nc; base += CH) {
                #pragma unroll
                for (int j = 0; j < CH; ++j) {   // prefetch next chunk (clamped)
                    int ind = cind[qH + min(base + CH + j, nc - 1)];
                    xnxt[j] = BF16X ? bf2f(xb[(size_t)ind * CIN + c])
                                    : xf[(size_t)ind * CIN + c];
                }
                #pragma unroll
                for (int j = 0; j < CH; ++j) {
                    if (base + j < nc) {         // wave-uniform predicate
                        const f32x4* wr = (const f32x4*)&w_p[(qH + base + j) * 16];
                        f32x4 w0 = wr[0], w1 = wr[1], w2 = wr[2], w3 = wr[3];
                        float xv = xcur[j];
                        acc[0]  += w0[0] * xv; acc[1]  += w0[1] * xv;
                        acc[2]  += w0[2] * xv; acc[3]  += w0[3] * xv;
                        acc[4]  += w1[0] * xv; acc[5]  += w1[1] * xv;
                        acc[6]  += w1[2] * xv; acc[7]  += w1[3] * xv;
                        acc[8]  += w2[0] * xv; acc[9]  += w2[1] * xv;
                        acc[10] += w2[2] * xv; acc[11] += w2[3] * xv;
                        acc[12] += w3[0] * xv; acc[13] += w3[1] * xv;
                        acc[14] += w3[2] * xv;
                    }
                }
                #pragma unroll
                for (int j = 0; j < CH; ++j) xcur[j] = xnxt[j];
            }
        }
        #pragma unroll
        for (int k = 0; k < KKP; ++k)
            WF16[q * SWF + k * 64 + c] = f2bf(acc[k]);     // stride-1 b16 writes
    }
    __syncthreads();

    // ---------------- Phase C: out[q][o] via MFMA, 6-deep wb prefetch ----------
    {
        const int lane = tid & 63;
        const int qrow = lane & 7;
        const int kg   = lane >> 4;
        const int ot0  = wid * 2;
        f32x4 c0 = {0.f,0.f,0.f,0.f}, c1 = {0.f,0.f,0.f,0.f};
        const ushort_t* wfrow = &WF16[qrow * SWF + kg * 8];
        const ushort_t* bbase = wb + ((size_t)(ot0 * 64 + lane)) * 8;

        bf16x8 rb0[6], rb1[6];
        #pragma unroll
        for (int i = 0; i < 6; ++i) {        // preload jt = 0..5
            rb0[i] = *(const bf16x8*)&bbase[(size_t)i * 4096];
            rb1[i] = *(const bf16x8*)&bbase[(size_t)i * 4096 + 512];
        }
        for (int m = 0; m < 5; ++m) {        // 5 x 6 = 30 jt steps
            #pragma unroll
            for (int u = 0; u < 6; ++u) {
                int jt = m * 6 + u;
                bf16x8 a = *(const bf16x8*)&wfrow[jt * 32];
                c0 = __builtin_amdgcn_mfma_f32_16x16x32_bf16(a, rb0[u], c0, 0, 0, 0);
                c1 = __builtin_amdgcn_mfma_f32_16x16x32_bf16(a, rb1[u], c1, 0, 0, 0);
                if (m < 4) {                 // prefetch jt+6 into freed slot
                    rb0[u] = *(const bf16x8*)&bbase[(size_t)(jt + 6) * 4096];
                    rb1[u] = *(const bf16x8*)&bbase[(size_t)(jt + 6) * 4096 + 512];
                }
            }
        }

        // C/D layout: col = lane&15, row = (lane>>4)*4 + reg. Rows 0..7 = queries.
        if (lane < 32) {
            int col = ot0 * 16 + (lane & 15);
            #pragma unroll
            for (int reg = 0; reg < 4; ++reg) {
                int row = (lane >> 4) * 4 + reg;
                float inv = 1.0f / (float)max(cnt[row], 1);
                int gq = q0 + row;
                if (gq < N) {
                    out[(size_t)gq * COUT + col]      = c0[reg] * inv;
                    out[(size_t)gq * COUT + col + 16] = c1[reg] * inv;
                }
            }
        }
    }
}

extern "C" void kernel_launch(void* const* d_in, const int* in_sizes, int n_in,
                              void* d_out, int out_size, void* d_ws, size_t ws_size,
                              hipStream_t stream) {
    const float* q_pts  = (const float*)d_in[0];
    const float* s_pts  = (const float*)d_in[1];
    const int*   nbinds = (const int*)d_in[2];
    const float* x      = (const float*)d_in[3];
    const float* kp     = (const float*)d_in[4];
    const float* wmat   = (const float*)d_in[5];
    float* out = (float*)d_out;
    int N = in_sizes[0] / 3;
    int M = in_sizes[1] / 3;

    // workspace carve: rowsum (M f32) | wb (245760 B) | xb (M*64 bf16)
    size_t    off_wb = ((size_t)M * 4 + 255) & ~(size_t)255;
    size_t    off_xb = (off_wb + 245760 + 255) & ~(size_t)255;
    size_t    need   = off_xb + (size_t)M * CIN * 2;
    float*    rowsum = (float*)d_ws;
    ushort_t* wb     = (ushort_t*)((char*)d_ws + off_wb);
    ushort_t* xb     = (ushort_t*)((char*)d_ws + off_xb);
    bool use_bf16x = (ws_size >= need);

    prep_kernel<<<(M + 3) / 4, 256, 0, stream>>>(x, rowsum, xb, M, use_bf16x ? 1 : 0);
    wprep_kernel<<<60, 256, 0, stream>>>(wmat, wb);
    int mb = (N + QB - 1) / QB;
    if (use_bf16x)
        kpconv_main<true><<<mb, 256, 0, stream>>>(q_pts, s_pts, nbinds, x, xb, kp,
                                                  wb, rowsum, out, N, M);
    else
        kpconv_main<false><<<mb, 256, 0, stream>>>(q_pts, s_pts, nbinds, x, xb, kp,
                                                   wb, rowsum, out, N, M);
}